// Round 5
// baseline (879.611 us; speedup 1.0000x reference)
//
#include <hip/hip_runtime.h>
#include <math.h>

#define HID 128
#define HEADS 4
#define NEG_SLOPE 0.2f

typedef short bf16x8 __attribute__((ext_vector_type(8)));   // 8 bf16 in 4 VGPRs
typedef float f32x4 __attribute__((ext_vector_type(4)));

// ---------------- CSR build ----------------

__global__ __launch_bounds__(256) void k_zero_int(int* p, int n) {
    int i = blockIdx.x * blockDim.x + threadIdx.x;
    if (i < n) p[i] = 0;
}

__global__ __launch_bounds__(256) void k_hist(const int* __restrict__ dst, int E, int* __restrict__ counts) {
    int e = blockIdx.x * blockDim.x + threadIdx.x;
    if (e < E) atomicAdd(&counts[dst[e]], 1);
}

__global__ __launch_bounds__(256) void k_scan_block(const int* __restrict__ counts, int N,
                                                    int* __restrict__ scanout, int* __restrict__ partials) {
    __shared__ int buf[256];
    int tid = threadIdx.x;
    int i = blockIdx.x * 256 + tid;
    int v = (i < N) ? counts[i] : 0;
    buf[tid] = v;
    __syncthreads();
    for (int off = 1; off < 256; off <<= 1) {
        int t = (tid >= off) ? buf[tid - off] : 0;
        __syncthreads();
        buf[tid] += t;
        __syncthreads();
    }
    if (i < N) scanout[i] = buf[tid] - v;
    if (tid == 255) partials[blockIdx.x] = buf[255];
}

__global__ __launch_bounds__(256) void k_scan_part(int* __restrict__ partials, int nb) {
    __shared__ int buf[256];
    int tid = threadIdx.x;
    int v = (tid < nb) ? partials[tid] : 0;
    buf[tid] = v;
    __syncthreads();
    for (int off = 1; off < 256; off <<= 1) {
        int t = (tid >= off) ? buf[tid - off] : 0;
        __syncthreads();
        buf[tid] += t;
        __syncthreads();
    }
    if (tid < nb) partials[tid] = buf[tid] - v;
}

__global__ __launch_bounds__(256) void k_scan_add(const int* __restrict__ scanout, const int* __restrict__ partials,
                                                  int N, int E, int* __restrict__ rowptr, int* __restrict__ nextp) {
    int i = blockIdx.x * 256 + threadIdx.x;
    if (i < N) {
        int r = scanout[i] + partials[blockIdx.x];
        rowptr[i] = r;
        nextp[i] = r;
    }
    if (i == 0) rowptr[N] = E;
}

__global__ __launch_bounds__(256) void k_scatter(const int* __restrict__ src, const int* __restrict__ dst, int E,
                                                 int* __restrict__ nextp, int* __restrict__ csr_src) {
    int e = blockIdx.x * blockDim.x + threadIdx.x;
    if (e < E) {
        int d = dst[e];
        int pos = atomicAdd(&nextp[d], 1);
        csr_src[pos] = src[e];
    }
}

// ---------------- fp32 -> bf16 (hi, lo) split helpers ----------------

__device__ inline unsigned short f2bf(float f) {
    unsigned u = __float_as_uint(f);
    unsigned r = (u + 0x7FFF + ((u >> 16) & 1)) >> 16;
    return (unsigned short)r;
}
__device__ inline float bf2f(unsigned short h) {
    return __uint_as_float(((unsigned)h) << 16);
}

// weight split (runs twice per launch, small)
__global__ __launch_bounds__(256) void k_tobf16(const float* __restrict__ x,
                                                unsigned short* __restrict__ hi,
                                                unsigned short* __restrict__ lo, int n) {
    int i = blockIdx.x * 256 + threadIdx.x;
    int base = i * 4;
    if (base >= n) return;
    float4 v = *(const float4*)(x + base);
    float f[4] = {v.x, v.y, v.z, v.w};
    ushort4 h, l;
    unsigned short hh[4], ll[4];
    #pragma unroll
    for (int q = 0; q < 4; q++) {
        unsigned short a = f2bf(f[q]);
        hh[q] = a;
        ll[q] = f2bf(f[q] - bf2f(a));
    }
    h.x = hh[0]; h.y = hh[1]; h.z = hh[2]; h.w = hh[3];
    l.x = ll[0]; l.y = ll[1]; l.z = ll[2]; l.w = ll[3];
    *(ushort4*)(hi + base) = h;
    *(ushort4*)(lo + base) = l;
}

// ---------------- MFMA linear (single pass): xl = x@Wl.T+bl ; xr = x@Wr.T+br ----------------
// Split-precision: x*W ~= xh*Wh + xh*Wl + xl*Wh (bf16 MFMA, fp32 accumulate).
// Wave = 16 nodes x 256 outputs (8 subtiles Wl + 8 subtiles Wr) so x hi/lo is
// fetched exactly once from HBM. Block = 128 threads (2 waves), grid = N/32.
// A frag: A[m=lane&15][k=quad*8+j]; B frag: W row n=lane&15, k contiguous.
// C/D: col=lane&15, row=quad*4+reg  (verified m89 mapping).

__global__ __launch_bounds__(128) void k_linear_mfma(
        const unsigned short* __restrict__ xhi, const unsigned short* __restrict__ xlo,
        const unsigned short* __restrict__ whiL, const unsigned short* __restrict__ wloL,
        const unsigned short* __restrict__ whiR, const unsigned short* __restrict__ wloR,
        const float* __restrict__ bl, const float* __restrict__ br,
        float* __restrict__ xl, float* __restrict__ xr, int N) {
    const int wave = threadIdx.x >> 6;
    const int lane = threadIdx.x & 63;
    const int l16  = lane & 15;
    const int quad = lane >> 4;
    const int n0   = blockIdx.x * 32 + wave * 16;

    int arow = n0 + l16;
    if (arow >= N) arow = N - 1;       // clamp loads; stores guarded below

    f32x4 accL[8], accR[8];
    #pragma unroll
    for (int s = 0; s < 8; s++) {
        accL[s] = (f32x4){0.f, 0.f, 0.f, 0.f};
        accR[s] = (f32x4){0.f, 0.f, 0.f, 0.f};
    }

    #pragma unroll
    for (int k0 = 0; k0 < HID; k0 += 32) {
        const int aoff = arow * HID + k0 + quad * 8;
        bf16x8 ahi = *(const bf16x8*)(xhi + aoff);
        bf16x8 alo = *(const bf16x8*)(xlo + aoff);
        #pragma unroll
        for (int s = 0; s < 8; s++) {
            const int boff = (s * 16 + l16) * HID + k0 + quad * 8;
            bf16x8 bhiL = *(const bf16x8*)(whiL + boff);
            bf16x8 bloL = *(const bf16x8*)(wloL + boff);
            accL[s] = __builtin_amdgcn_mfma_f32_16x16x32_bf16(ahi, bhiL, accL[s], 0, 0, 0);
            accL[s] = __builtin_amdgcn_mfma_f32_16x16x32_bf16(ahi, bloL, accL[s], 0, 0, 0);
            accL[s] = __builtin_amdgcn_mfma_f32_16x16x32_bf16(alo, bhiL, accL[s], 0, 0, 0);
            bf16x8 bhiR = *(const bf16x8*)(whiR + boff);
            bf16x8 bloR = *(const bf16x8*)(wloR + boff);
            accR[s] = __builtin_amdgcn_mfma_f32_16x16x32_bf16(ahi, bhiR, accR[s], 0, 0, 0);
            accR[s] = __builtin_amdgcn_mfma_f32_16x16x32_bf16(ahi, bloR, accR[s], 0, 0, 0);
            accR[s] = __builtin_amdgcn_mfma_f32_16x16x32_bf16(alo, bhiR, accR[s], 0, 0, 0);
        }
    }

    #pragma unroll
    for (int s = 0; s < 8; s++) {
        int col = s * 16 + l16;
        float bvL = bl[col];
        float bvR = br[col];
        #pragma unroll
        for (int r = 0; r < 4; r++) {
            int node = n0 + quad * 4 + r;
            if (node < N) {
                xl[(size_t)node * HID + col] = accL[s][r] + bvL;
                xr[(size_t)node * HID + col] = accR[s][r] + bvR;
            }
        }
    }
}

// ---------------- Fused attention: wave per node, 2 edge streams, online softmax ----------------
// Epilogue also emits the bf16 hi/lo split of the output (input of next linear).

__global__ __launch_bounds__(256) void k_attn(const float* __restrict__ xl, const float* __restrict__ xr,
                                              const int* __restrict__ rowptr, const int* __restrict__ csr_src,
                                              const float* __restrict__ att, const float* __restrict__ bias,
                                              const float* __restrict__ x_res, float* __restrict__ out,
                                              unsigned short* __restrict__ xhi, unsigned short* __restrict__ xlo,
                                              int add_res, int want_split, int N) {
    const int wave = threadIdx.x >> 6;
    const int lane = threadIdx.x & 63;
    const int sub  = lane >> 5;          // edge stream 0/1
    const int l32  = lane & 31;          // channels [4*l32, 4*l32+4); head = l32>>3
    const int n = blockIdx.x * 4 + wave;
    if (n >= N) return;

    const float4 a4  = *(const float4*)(att + 4 * l32);
    const float4 xr4 = *(const float4*)(xr + (size_t)n * HID + 4 * l32);
    const int s0 = rowptr[n], s1 = rowptr[n + 1];

    float m = -INFINITY, den = 0.f;
    float4 acc = make_float4(0.f, 0.f, 0.f, 0.f);

    int j = s0 + sub;
    float4 xlv = make_float4(0.f, 0.f, 0.f, 0.f);
    if (j < s1) xlv = *(const float4*)(xl + (size_t)csr_src[j] * HID + 4 * l32);
    while (j < s1) {
        float4 cur = xlv;
        int jn = j + 2;
        if (jn < s1) xlv = *(const float4*)(xl + (size_t)csr_src[jn] * HID + 4 * l32);
        float e0 = cur.x + xr4.x; e0 = e0 > 0.f ? e0 : NEG_SLOPE * e0;
        float e1 = cur.y + xr4.y; e1 = e1 > 0.f ? e1 : NEG_SLOPE * e1;
        float e2 = cur.z + xr4.z; e2 = e2 > 0.f ? e2 : NEG_SLOPE * e2;
        float e3 = cur.w + xr4.w; e3 = e3 > 0.f ? e3 : NEG_SLOPE * e3;
        float p = e0 * a4.x + e1 * a4.y + e2 * a4.z + e3 * a4.w;
        p += __shfl_xor(p, 1);           // reduce 8-lane head group
        p += __shfl_xor(p, 2);
        p += __shfl_xor(p, 4);
        float nm = fmaxf(m, p);
        float sc = __expf(m - nm);
        float w  = __expf(p - nm);
        den = den * sc + w;
        acc.x = acc.x * sc + w * cur.x;
        acc.y = acc.y * sc + w * cur.y;
        acc.z = acc.z * sc + w * cur.z;
        acc.w = acc.w * sc + w * cur.w;
        m = nm;
        j = jn;
    }

    // merge the two streams across the half-wave boundary
    float m2   = __shfl_xor(m, 32);
    float den2 = __shfl_xor(den, 32);
    float4 acc2;
    acc2.x = __shfl_xor(acc.x, 32);
    acc2.y = __shfl_xor(acc.y, 32);
    acc2.z = __shfl_xor(acc.z, 32);
    acc2.w = __shfl_xor(acc.w, 32);
    float nm = fmaxf(m, m2);
    float sA = __expf(m - nm), sB = __expf(m2 - nm);
    den = den * sA + den2 * sB;
    acc.x = acc.x * sA + acc2.x * sB;
    acc.y = acc.y * sA + acc2.y * sB;
    acc.z = acc.z * sA + acc2.z * sB;
    acc.w = acc.w * sA + acc2.w * sB;

    if (sub == 0) {
        float4 b4 = *(const float4*)(bias + 4 * l32);
        float inv = (den > 0.f) ? 1.f / den : 0.f;
        float4 v;
        v.x = fmaxf(acc.x * inv + b4.x, 0.f);
        v.y = fmaxf(acc.y * inv + b4.y, 0.f);
        v.z = fmaxf(acc.z * inv + b4.z, 0.f);
        v.w = fmaxf(acc.w * inv + b4.w, 0.f);
        if (add_res) {
            float4 r4 = *(const float4*)(x_res + (size_t)n * HID + 4 * l32);
            v.x += r4.x; v.y += r4.y; v.z += r4.z; v.w += r4.w;
        }
        *(float4*)(out + (size_t)n * HID + 4 * l32) = v;
        if (want_split) {
            float f[4] = {v.x, v.y, v.z, v.w};
            unsigned short hh[4], ll[4];
            #pragma unroll
            for (int q = 0; q < 4; q++) {
                unsigned short a = f2bf(f[q]);
                hh[q] = a;
                ll[q] = f2bf(f[q] - bf2f(a));
            }
            ushort4 h4, l4;
            h4.x = hh[0]; h4.y = hh[1]; h4.z = hh[2]; h4.w = hh[3];
            l4.x = ll[0]; l4.y = ll[1]; l4.z = ll[2]; l4.w = ll[3];
            *(ushort4*)(xhi + (size_t)n * HID + 4 * l32) = h4;
            *(ushort4*)(xlo + (size_t)n * HID + 4 * l32) = l4;
        }
    }
}

// ---------------- Embedding: x = relu(nf @ W_emb.T + b_emb)  (+ bf16 split) ----------------

__global__ __launch_bounds__(128) void k_embed(const float* __restrict__ nf, const float* __restrict__ W,
                                               const float* __restrict__ b, float* __restrict__ x,
                                               unsigned short* __restrict__ xhi, unsigned short* __restrict__ xlo,
                                               int N) {
    __shared__ float f[11];
    int n = blockIdx.x;
    int h = threadIdx.x;
    if (h < 11) f[h] = nf[(size_t)n * 11 + h];
    __syncthreads();
    float acc = b[h];
    #pragma unroll
    for (int k = 0; k < 11; k++) acc += f[k] * W[h * 11 + k];
    float v = fmaxf(acc, 0.f);
    x[(size_t)n * HID + h] = v;
    unsigned short hh = f2bf(v);
    xhi[(size_t)n * HID + h] = hh;
    xlo[(size_t)n * HID + h] = f2bf(v - bf2f(hh));
}

// ---------------- Graph readout: mean + max over nodes ----------------

__global__ __launch_bounds__(128) void k_reduce1(const float* __restrict__ x, int N,
                                                 float* __restrict__ psum, float* __restrict__ pmax) {
    int b = blockIdx.x;
    int h = threadIdx.x;
    int per = (N + gridDim.x - 1) / gridDim.x;
    int n0 = b * per, n1 = min(N, n0 + per);
    float s = 0.f, m = -INFINITY;
    for (int n = n0; n < n1; n++) {
        float v = x[(size_t)n * HID + h];
        s += v;
        m = fmaxf(m, v);
    }
    psum[b * HID + h] = s;
    pmax[b * HID + h] = m;
}

__global__ __launch_bounds__(128) void k_reduce2(const float* __restrict__ psum, const float* __restrict__ pmax,
                                                 int nb, float* __restrict__ out, float invN) {
    int h = threadIdx.x;
    float s = 0.f, m = -INFINITY;
    for (int b = 0; b < nb; b++) {
        s += psum[b * HID + h];
        m = fmaxf(m, pmax[b * HID + h]);
    }
    out[h] = s * invN;
    out[HID + h] = m;
}

// ---------------- Launch ----------------

extern "C" void kernel_launch(void* const* d_in, const int* in_sizes, int n_in,
                              void* d_out, int out_size, void* d_ws, size_t ws_size,
                              hipStream_t stream) {
    const float* nf    = (const float*)d_in[0];
    const int*   ei    = (const int*)d_in[1];
    const float* W_emb = (const float*)d_in[3];
    const float* b_emb = (const float*)d_in[4];
    const float* Wl    = (const float*)d_in[5];
    const float* bl    = (const float*)d_in[6];
    const float* Wr    = (const float*)d_in[7];
    const float* br    = (const float*)d_in[8];
    const float* att   = (const float*)d_in[9];
    const float* bias  = (const float*)d_in[10];

    const int N = in_sizes[0] / 11;
    const int E = in_sizes[1] / 2;
    const int* src = ei;
    const int* dst = ei + E;

    float* out  = (float*)d_out;
    float* xout = out + 2 * HID;

    // workspace carve-up
    char* w = (char*)d_ws;
    float* x        = (float*)w; w += (size_t)N * HID * 4;
    float* xl       = (float*)w; w += (size_t)N * HID * 4;
    float* xr       = (float*)w; w += (size_t)N * HID * 4;
    unsigned short* xhi = (unsigned short*)w; w += (size_t)N * HID * 2;
    unsigned short* xlo = (unsigned short*)w; w += (size_t)N * HID * 2;
    unsigned short* whiL = (unsigned short*)w; w += (size_t)4 * HID * HID * 2;
    unsigned short* wloL = (unsigned short*)w; w += (size_t)4 * HID * HID * 2;
    unsigned short* whiR = (unsigned short*)w; w += (size_t)4 * HID * HID * 2;
    unsigned short* wloR = (unsigned short*)w; w += (size_t)4 * HID * HID * 2;
    int*   counts   = (int*)w;   w += (size_t)N * 4;
    int*   scanout  = (int*)w;   w += (size_t)N * 4;
    int*   rowptr   = (int*)w;   w += (size_t)(N + 1) * 4;
    int*   nextp    = (int*)w;   w += (size_t)N * 4;
    int*   partials = (int*)w;   w += (size_t)256 * 4;
    int*   csr_src  = (int*)w;   w += (size_t)E * 4;
    float* psum     = (float*)w; w += (size_t)256 * HID * 4;
    float* pmax     = (float*)w; w += (size_t)256 * HID * 4;

    const int nb = (N + 255) / 256;
    const int nW = 4 * HID * HID;

    // weight bf16 split (once per launch)
    k_tobf16<<<(nW / 4 + 255) / 256, 256, 0, stream>>>(Wl, whiL, wloL, nW);
    k_tobf16<<<(nW / 4 + 255) / 256, 256, 0, stream>>>(Wr, whiR, wloR, nW);

    // CSR build
    k_zero_int<<<nb, 256, 0, stream>>>(counts, N);
    k_hist<<<(E + 255) / 256, 256, 0, stream>>>(dst, E, counts);
    k_scan_block<<<nb, 256, 0, stream>>>(counts, N, scanout, partials);
    k_scan_part<<<1, 256, 0, stream>>>(partials, nb);
    k_scan_add<<<nb, 256, 0, stream>>>(scanout, partials, N, E, rowptr, nextp);
    k_scatter<<<(E + 255) / 256, 256, 0, stream>>>(src, dst, E, nextp, csr_src);

    // embedding (+ bf16 split of x)
    k_embed<<<N, 128, 0, stream>>>(nf, W_emb, b_emb, x, xhi, xlo, N);

    for (int i = 0; i < 4; i++) {
        k_linear_mfma<<<(N + 31) / 32, 128, 0, stream>>>(xhi, xlo,
                                                 whiL + (size_t)i * HID * HID, wloL + (size_t)i * HID * HID,
                                                 whiR + (size_t)i * HID * HID, wloR + (size_t)i * HID * HID,
                                                 bl + i * HID, br + i * HID, xl, xr, N);
        float* dest = (i == 3) ? xout : x;
        k_attn<<<(N + 3) / 4, 256, 0, stream>>>(xl, xr, rowptr, csr_src,
                                                att + i * HEADS * 32, bias + i * HID,
                                                x, dest, xhi, xlo,
                                                i > 0 ? 1 : 0, i < 3 ? 1 : 0, N);
    }

    k_reduce1<<<256, 128, 0, stream>>>(xout, N, psum, pmax);
    k_reduce2<<<1, 128, 0, stream>>>(psum, pmax, 256, out, 1.0f / N);
}

// Round 6
// 699.057 us; speedup vs baseline: 1.2583x; 1.2583x over previous
//
#include <hip/hip_runtime.h>
#include <math.h>

#define HID 128
#define HEADS 4
#define NEG_SLOPE 0.2f

typedef short bf16x8 __attribute__((ext_vector_type(8)));   // 8 bf16 in 4 VGPRs
typedef float f32x4 __attribute__((ext_vector_type(4)));

// ---------------- CSR build ----------------

__global__ __launch_bounds__(256) void k_zero_int(int* p, int n) {
    int i = blockIdx.x * blockDim.x + threadIdx.x;
    if (i < n) p[i] = 0;
}

__global__ __launch_bounds__(256) void k_hist(const int* __restrict__ dst, int E, int* __restrict__ counts) {
    int e = blockIdx.x * blockDim.x + threadIdx.x;
    if (e < E) atomicAdd(&counts[dst[e]], 1);
}

__global__ __launch_bounds__(256) void k_scan_block(const int* __restrict__ counts, int N,
                                                    int* __restrict__ scanout, int* __restrict__ partials) {
    __shared__ int buf[256];
    int tid = threadIdx.x;
    int i = blockIdx.x * 256 + tid;
    int v = (i < N) ? counts[i] : 0;
    buf[tid] = v;
    __syncthreads();
    for (int off = 1; off < 256; off <<= 1) {
        int t = (tid >= off) ? buf[tid - off] : 0;
        __syncthreads();
        buf[tid] += t;
        __syncthreads();
    }
    if (i < N) scanout[i] = buf[tid] - v;
    if (tid == 255) partials[blockIdx.x] = buf[255];
}

__global__ __launch_bounds__(256) void k_scan_part(int* __restrict__ partials, int nb) {
    __shared__ int buf[256];
    int tid = threadIdx.x;
    int v = (tid < nb) ? partials[tid] : 0;
    buf[tid] = v;
    __syncthreads();
    for (int off = 1; off < 256; off <<= 1) {
        int t = (tid >= off) ? buf[tid - off] : 0;
        __syncthreads();
        buf[tid] += t;
        __syncthreads();
    }
    if (tid < nb) partials[tid] = buf[tid] - v;
}

__global__ __launch_bounds__(256) void k_scan_add(const int* __restrict__ scanout, const int* __restrict__ partials,
                                                  int N, int E, int* __restrict__ rowptr, int* __restrict__ nextp) {
    int i = blockIdx.x * 256 + threadIdx.x;
    if (i < N) {
        int r = scanout[i] + partials[blockIdx.x];
        rowptr[i] = r;
        nextp[i] = r;
    }
    if (i == 0) rowptr[N] = E;
}

__global__ __launch_bounds__(256) void k_scatter(const int* __restrict__ src, const int* __restrict__ dst, int E,
                                                 int* __restrict__ nextp, int* __restrict__ csr_src) {
    int e = blockIdx.x * blockDim.x + threadIdx.x;
    if (e < E) {
        int d = dst[e];
        int pos = atomicAdd(&nextp[d], 1);
        csr_src[pos] = src[e];
    }
}

// ---------------- fp32 -> bf16 (hi, lo) split helpers ----------------

__device__ inline unsigned short f2bf(float f) {
    unsigned u = __float_as_uint(f);
    unsigned r = (u + 0x7FFF + ((u >> 16) & 1)) >> 16;
    return (unsigned short)r;
}
__device__ inline float bf2f(unsigned short h) {
    return __uint_as_float(((unsigned)h) << 16);
}

// weight split (runs twice per launch, small)
__global__ __launch_bounds__(256) void k_tobf16(const float* __restrict__ x,
                                                unsigned short* __restrict__ hi,
                                                unsigned short* __restrict__ lo, int n) {
    int i = blockIdx.x * 256 + threadIdx.x;
    int base = i * 4;
    if (base >= n) return;
    float4 v = *(const float4*)(x + base);
    float f[4] = {v.x, v.y, v.z, v.w};
    ushort4 h, l;
    unsigned short hh[4], ll[4];
    #pragma unroll
    for (int q = 0; q < 4; q++) {
        unsigned short a = f2bf(f[q]);
        hh[q] = a;
        ll[q] = f2bf(f[q] - bf2f(a));
    }
    h.x = hh[0]; h.y = hh[1]; h.z = hh[2]; h.w = hh[3];
    l.x = ll[0]; l.y = ll[1]; l.z = ll[2]; l.w = ll[3];
    *(ushort4*)(hi + base) = h;
    *(ushort4*)(lo + base) = l;
}

// ---------------- MFMA linear, LDS-resident W ----------------
// Split-precision: x*W ~= xh*Wh + xh*Wl + xl*Wh (bf16 MFMA, fp32 accumulate).
// blockIdx.y: 0 -> xl = x@Wl.T+bl ; 1 -> xr = x@Wr.T+br.
// Block = 512 threads (8 waves) = 128 nodes; W hi+lo (64 KB) staged in LDS
// with XOR-chunk swizzle (chunk cc of row r at cc^(r&7)) so the b128
// fragment reads hit all 32 banks at 2-way aliasing (free, m136).
// A frag: A[m=lane&15][k=quad*8+j]; B frag: W row n=lane&15, k contiguous.
// C/D: col=lane&15, row=quad*4+reg  (verified m89 mapping).

__global__ __launch_bounds__(512) void k_linear_mfma(
        const unsigned short* __restrict__ xhi, const unsigned short* __restrict__ xlo,
        const unsigned short* __restrict__ whiL, const unsigned short* __restrict__ wloL,
        const unsigned short* __restrict__ whiR, const unsigned short* __restrict__ wloR,
        const float* __restrict__ bl, const float* __restrict__ br,
        float* __restrict__ xl, float* __restrict__ xr, int N) {
    __shared__ unsigned short ldsh[16384];   // 32 KB: W hi, swizzled
    __shared__ unsigned short ldsl[16384];   // 32 KB: W lo, swizzled
    const int t   = threadIdx.x;
    const int mat = blockIdx.y;
    const unsigned short* Wh = mat ? whiR : whiL;
    const unsigned short* Wo = mat ? wloR : wloL;

    // stage W: 2048 16-B chunks per array; chunk g = (row r = g>>4, chunk cc = g&15)
    for (int g = t; g < 2048; g += 512) {
        int r = g >> 4, cc = g & 15;
        int dsto = r * 128 + ((cc ^ (r & 7)) << 3);      // ushort units
        *(float4*)&ldsh[dsto] = *(const float4*)(Wh + g * 8);
        *(float4*)&ldsl[dsto] = *(const float4*)(Wo + g * 8);
    }
    __syncthreads();

    const int wave = t >> 6;
    const int lane = t & 63;
    const int l16  = lane & 15;
    const int quad = lane >> 4;
    const int n0   = blockIdx.x * 128 + wave * 16;

    int arow = n0 + l16;
    if (arow >= N) arow = N - 1;       // clamp loads; stores guarded below

    f32x4 acc[8];
    #pragma unroll
    for (int s = 0; s < 8; s++) acc[s] = (f32x4){0.f, 0.f, 0.f, 0.f};

    #pragma unroll
    for (int k0 = 0; k0 < HID; k0 += 32) {
        const int aoff = arow * HID + k0 + quad * 8;
        bf16x8 ahi = *(const bf16x8*)(xhi + aoff);
        bf16x8 alo = *(const bf16x8*)(xlo + aoff);
        const int cc = (k0 >> 3) + quad;
        #pragma unroll
        for (int s = 0; s < 8; s++) {
            const int row = s * 16 + l16;
            const int off = row * 128 + ((cc ^ (l16 & 7)) << 3);
            bf16x8 bhi = *(const bf16x8*)&ldsh[off];
            bf16x8 blo = *(const bf16x8*)&ldsl[off];
            acc[s] = __builtin_amdgcn_mfma_f32_16x16x32_bf16(ahi, bhi, acc[s], 0, 0, 0);
            acc[s] = __builtin_amdgcn_mfma_f32_16x16x32_bf16(ahi, blo, acc[s], 0, 0, 0);
            acc[s] = __builtin_amdgcn_mfma_f32_16x16x32_bf16(alo, bhi, acc[s], 0, 0, 0);
        }
    }

    float* dst = mat ? xr : xl;
    const float* bias = mat ? br : bl;
    #pragma unroll
    for (int s = 0; s < 8; s++) {
        int col = s * 16 + l16;
        float bv = bias[col];
        #pragma unroll
        for (int r = 0; r < 4; r++) {
            int node = n0 + quad * 4 + r;
            if (node < N) dst[(size_t)node * HID + col] = acc[s][r] + bv;
        }
    }
}

// ---------------- Fused attention: wave per node, 2 edge streams, online softmax ----------------
// Epilogue also emits the bf16 hi/lo split of the output (input of next linear).

__global__ __launch_bounds__(256) void k_attn(const float* __restrict__ xl, const float* __restrict__ xr,
                                              const int* __restrict__ rowptr, const int* __restrict__ csr_src,
                                              const float* __restrict__ att, const float* __restrict__ bias,
                                              const float* __restrict__ x_res, float* __restrict__ out,
                                              unsigned short* __restrict__ xhi, unsigned short* __restrict__ xlo,
                                              int add_res, int want_split, int N) {
    const int wave = threadIdx.x >> 6;
    const int lane = threadIdx.x & 63;
    const int sub  = lane >> 5;          // edge stream 0/1
    const int l32  = lane & 31;          // channels [4*l32, 4*l32+4); head = l32>>3
    const int n = blockIdx.x * 4 + wave;
    if (n >= N) return;

    const float4 a4  = *(const float4*)(att + 4 * l32);
    const float4 xr4 = *(const float4*)(xr + (size_t)n * HID + 4 * l32);
    const int s0 = rowptr[n], s1 = rowptr[n + 1];

    float m = -INFINITY, den = 0.f;
    float4 acc = make_float4(0.f, 0.f, 0.f, 0.f);

    int j = s0 + sub;
    float4 xlv = make_float4(0.f, 0.f, 0.f, 0.f);
    if (j < s1) xlv = *(const float4*)(xl + (size_t)csr_src[j] * HID + 4 * l32);
    while (j < s1) {
        float4 cur = xlv;
        int jn = j + 2;
        if (jn < s1) xlv = *(const float4*)(xl + (size_t)csr_src[jn] * HID + 4 * l32);
        float e0 = cur.x + xr4.x; e0 = e0 > 0.f ? e0 : NEG_SLOPE * e0;
        float e1 = cur.y + xr4.y; e1 = e1 > 0.f ? e1 : NEG_SLOPE * e1;
        float e2 = cur.z + xr4.z; e2 = e2 > 0.f ? e2 : NEG_SLOPE * e2;
        float e3 = cur.w + xr4.w; e3 = e3 > 0.f ? e3 : NEG_SLOPE * e3;
        float p = e0 * a4.x + e1 * a4.y + e2 * a4.z + e3 * a4.w;
        p += __shfl_xor(p, 1);           // reduce 8-lane head group
        p += __shfl_xor(p, 2);
        p += __shfl_xor(p, 4);
        float nm = fmaxf(m, p);
        float sc = __expf(m - nm);
        float w  = __expf(p - nm);
        den = den * sc + w;
        acc.x = acc.x * sc + w * cur.x;
        acc.y = acc.y * sc + w * cur.y;
        acc.z = acc.z * sc + w * cur.z;
        acc.w = acc.w * sc + w * cur.w;
        m = nm;
        j = jn;
    }

    // merge the two streams across the half-wave boundary
    float m2   = __shfl_xor(m, 32);
    float den2 = __shfl_xor(den, 32);
    float4 acc2;
    acc2.x = __shfl_xor(acc.x, 32);
    acc2.y = __shfl_xor(acc.y, 32);
    acc2.z = __shfl_xor(acc.z, 32);
    acc2.w = __shfl_xor(acc.w, 32);
    float nm = fmaxf(m, m2);
    float sA = __expf(m - nm), sB = __expf(m2 - nm);
    den = den * sA + den2 * sB;
    acc.x = acc.x * sA + acc2.x * sB;
    acc.y = acc.y * sA + acc2.y * sB;
    acc.z = acc.z * sA + acc2.z * sB;
    acc.w = acc.w * sA + acc2.w * sB;

    if (sub == 0) {
        float4 b4 = *(const float4*)(bias + 4 * l32);
        float inv = (den > 0.f) ? 1.f / den : 0.f;
        float4 v;
        v.x = fmaxf(acc.x * inv + b4.x, 0.f);
        v.y = fmaxf(acc.y * inv + b4.y, 0.f);
        v.z = fmaxf(acc.z * inv + b4.z, 0.f);
        v.w = fmaxf(acc.w * inv + b4.w, 0.f);
        if (add_res) {
            float4 r4 = *(const float4*)(x_res + (size_t)n * HID + 4 * l32);
            v.x += r4.x; v.y += r4.y; v.z += r4.z; v.w += r4.w;
        }
        *(float4*)(out + (size_t)n * HID + 4 * l32) = v;
        if (want_split) {
            float f[4] = {v.x, v.y, v.z, v.w};
            unsigned short hh[4], ll[4];
            #pragma unroll
            for (int q = 0; q < 4; q++) {
                unsigned short a = f2bf(f[q]);
                hh[q] = a;
                ll[q] = f2bf(f[q] - bf2f(a));
            }
            ushort4 h4, l4;
            h4.x = hh[0]; h4.y = hh[1]; h4.z = hh[2]; h4.w = hh[3];
            l4.x = ll[0]; l4.y = ll[1]; l4.z = ll[2]; l4.w = ll[3];
            *(ushort4*)(xhi + (size_t)n * HID + 4 * l32) = h4;
            *(ushort4*)(xlo + (size_t)n * HID + 4 * l32) = l4;
        }
    }
}

// ---------------- Embedding: x = relu(nf @ W_emb.T + b_emb)  (+ bf16 split) ----------------

__global__ __launch_bounds__(128) void k_embed(const float* __restrict__ nf, const float* __restrict__ W,
                                               const float* __restrict__ b, float* __restrict__ x,
                                               unsigned short* __restrict__ xhi, unsigned short* __restrict__ xlo,
                                               int N) {
    __shared__ float f[11];
    int n = blockIdx.x;
    int h = threadIdx.x;
    if (h < 11) f[h] = nf[(size_t)n * 11 + h];
    __syncthreads();
    float acc = b[h];
    #pragma unroll
    for (int k = 0; k < 11; k++) acc += f[k] * W[h * 11 + k];
    float v = fmaxf(acc, 0.f);
    x[(size_t)n * HID + h] = v;
    unsigned short hh = f2bf(v);
    xhi[(size_t)n * HID + h] = hh;
    xlo[(size_t)n * HID + h] = f2bf(v - bf2f(hh));
}

// ---------------- Graph readout: mean + max over nodes ----------------

__global__ __launch_bounds__(128) void k_reduce1(const float* __restrict__ x, int N,
                                                 float* __restrict__ psum, float* __restrict__ pmax) {
    int b = blockIdx.x;
    int h = threadIdx.x;
    int per = (N + gridDim.x - 1) / gridDim.x;
    int n0 = b * per, n1 = min(N, n0 + per);
    float s = 0.f, m = -INFINITY;
    for (int n = n0; n < n1; n++) {
        float v = x[(size_t)n * HID + h];
        s += v;
        m = fmaxf(m, v);
    }
    psum[b * HID + h] = s;
    pmax[b * HID + h] = m;
}

__global__ __launch_bounds__(128) void k_reduce2(const float* __restrict__ psum, const float* __restrict__ pmax,
                                                 int nb, float* __restrict__ out, float invN) {
    int h = threadIdx.x;
    float s = 0.f, m = -INFINITY;
    for (int b = 0; b < nb; b++) {
        s += psum[b * HID + h];
        m = fmaxf(m, pmax[b * HID + h]);
    }
    out[h] = s * invN;
    out[HID + h] = m;
}

// ---------------- Launch ----------------

extern "C" void kernel_launch(void* const* d_in, const int* in_sizes, int n_in,
                              void* d_out, int out_size, void* d_ws, size_t ws_size,
                              hipStream_t stream) {
    const float* nf    = (const float*)d_in[0];
    const int*   ei    = (const int*)d_in[1];
    const float* W_emb = (const float*)d_in[3];
    const float* b_emb = (const float*)d_in[4];
    const float* Wl    = (const float*)d_in[5];
    const float* bl    = (const float*)d_in[6];
    const float* Wr    = (const float*)d_in[7];
    const float* br    = (const float*)d_in[8];
    const float* att   = (const float*)d_in[9];
    const float* bias  = (const float*)d_in[10];

    const int N = in_sizes[0] / 11;
    const int E = in_sizes[1] / 2;
    const int* src = ei;
    const int* dst = ei + E;

    float* out  = (float*)d_out;
    float* xout = out + 2 * HID;

    // workspace carve-up
    char* w = (char*)d_ws;
    float* x        = (float*)w; w += (size_t)N * HID * 4;
    float* xl       = (float*)w; w += (size_t)N * HID * 4;
    float* xr       = (float*)w; w += (size_t)N * HID * 4;
    unsigned short* xhi = (unsigned short*)w; w += (size_t)N * HID * 2;
    unsigned short* xlo = (unsigned short*)w; w += (size_t)N * HID * 2;
    unsigned short* whiL = (unsigned short*)w; w += (size_t)4 * HID * HID * 2;
    unsigned short* wloL = (unsigned short*)w; w += (size_t)4 * HID * HID * 2;
    unsigned short* whiR = (unsigned short*)w; w += (size_t)4 * HID * HID * 2;
    unsigned short* wloR = (unsigned short*)w; w += (size_t)4 * HID * HID * 2;
    int*   counts   = (int*)w;   w += (size_t)N * 4;
    int*   scanout  = (int*)w;   w += (size_t)N * 4;
    int*   rowptr   = (int*)w;   w += (size_t)(N + 1) * 4;
    int*   nextp    = (int*)w;   w += (size_t)N * 4;
    int*   partials = (int*)w;   w += (size_t)256 * 4;
    int*   csr_src  = (int*)w;   w += (size_t)E * 4;
    float* psum     = (float*)w; w += (size_t)256 * HID * 4;
    float* pmax     = (float*)w; w += (size_t)256 * HID * 4;

    const int nb = (N + 255) / 256;
    const int nW = 4 * HID * HID;

    // weight bf16 split (once per launch)
    k_tobf16<<<(nW / 4 + 255) / 256, 256, 0, stream>>>(Wl, whiL, wloL, nW);
    k_tobf16<<<(nW / 4 + 255) / 256, 256, 0, stream>>>(Wr, whiR, wloR, nW);

    // CSR build
    k_zero_int<<<nb, 256, 0, stream>>>(counts, N);
    k_hist<<<(E + 255) / 256, 256, 0, stream>>>(dst, E, counts);
    k_scan_block<<<nb, 256, 0, stream>>>(counts, N, scanout, partials);
    k_scan_part<<<1, 256, 0, stream>>>(partials, nb);
    k_scan_add<<<nb, 256, 0, stream>>>(scanout, partials, N, E, rowptr, nextp);
    k_scatter<<<(E + 255) / 256, 256, 0, stream>>>(src, dst, E, nextp, csr_src);

    // embedding (+ bf16 split of x)
    k_embed<<<N, 128, 0, stream>>>(nf, W_emb, b_emb, x, xhi, xlo, N);

    dim3 lgrid((N + 127) / 128, 2);
    for (int i = 0; i < 4; i++) {
        k_linear_mfma<<<lgrid, 512, 0, stream>>>(xhi, xlo,
                                                 whiL + (size_t)i * HID * HID, wloL + (size_t)i * HID * HID,
                                                 whiR + (size_t)i * HID * HID, wloR + (size_t)i * HID * HID,
                                                 bl + i * HID, br + i * HID, xl, xr, N);
        float* dest = (i == 3) ? xout : x;
        k_attn<<<(N + 3) / 4, 256, 0, stream>>>(xl, xr, rowptr, csr_src,
                                                att + i * HEADS * 32, bias + i * HID,
                                                x, dest, xhi, xlo,
                                                i > 0 ? 1 : 0, i < 3 ? 1 : 0, N);
    }

    k_reduce1<<<256, 128, 0, stream>>>(xout, N, psum, pmax);
    k_reduce2<<<1, 128, 0, stream>>>(psum, pmax, 256, out, 1.0f / N);
}

// Round 7
// 671.356 us; speedup vs baseline: 1.3102x; 1.0413x over previous
//
#include <hip/hip_runtime.h>
#include <math.h>

#define HID 128
#define HEADS 4
#define NEG_SLOPE 0.2f

typedef short bf16x8 __attribute__((ext_vector_type(8)));   // 8 bf16 in 4 VGPRs
typedef float f32x4 __attribute__((ext_vector_type(4)));
typedef _Float16 f16x4 __attribute__((ext_vector_type(4)));

// ---------------- CSR build ----------------

__global__ __launch_bounds__(256) void k_zero_int(int* p, int n) {
    int i = blockIdx.x * blockDim.x + threadIdx.x;
    if (i < n) p[i] = 0;
}

__global__ __launch_bounds__(256) void k_hist(const int* __restrict__ dst, int E, int* __restrict__ counts) {
    int e = blockIdx.x * blockDim.x + threadIdx.x;
    if (e < E) atomicAdd(&counts[dst[e]], 1);
}

__global__ __launch_bounds__(256) void k_scan_block(const int* __restrict__ counts, int N,
                                                    int* __restrict__ scanout, int* __restrict__ partials) {
    __shared__ int buf[256];
    int tid = threadIdx.x;
    int i = blockIdx.x * 256 + tid;
    int v = (i < N) ? counts[i] : 0;
    buf[tid] = v;
    __syncthreads();
    for (int off = 1; off < 256; off <<= 1) {
        int t = (tid >= off) ? buf[tid - off] : 0;
        __syncthreads();
        buf[tid] += t;
        __syncthreads();
    }
    if (i < N) scanout[i] = buf[tid] - v;
    if (tid == 255) partials[blockIdx.x] = buf[255];
}

__global__ __launch_bounds__(256) void k_scan_part(int* __restrict__ partials, int nb) {
    __shared__ int buf[256];
    int tid = threadIdx.x;
    int v = (tid < nb) ? partials[tid] : 0;
    buf[tid] = v;
    __syncthreads();
    for (int off = 1; off < 256; off <<= 1) {
        int t = (tid >= off) ? buf[tid - off] : 0;
        __syncthreads();
        buf[tid] += t;
        __syncthreads();
    }
    if (tid < nb) partials[tid] = buf[tid] - v;
}

__global__ __launch_bounds__(256) void k_scan_add(const int* __restrict__ scanout, const int* __restrict__ partials,
                                                  int N, int E, int* __restrict__ rowptr, int* __restrict__ nextp) {
    int i = blockIdx.x * 256 + threadIdx.x;
    if (i < N) {
        int r = scanout[i] + partials[blockIdx.x];
        rowptr[i] = r;
        nextp[i] = r;
    }
    if (i == 0) rowptr[N] = E;
}

__global__ __launch_bounds__(256) void k_scatter(const int* __restrict__ src, const int* __restrict__ dst, int E,
                                                 int* __restrict__ nextp, int* __restrict__ csr_src) {
    int e = blockIdx.x * blockDim.x + threadIdx.x;
    if (e < E) {
        int d = dst[e];
        int pos = atomicAdd(&nextp[d], 1);
        csr_src[pos] = src[e];
    }
}

// ---------------- fp32 -> bf16 (hi, lo) split helpers ----------------

__device__ inline unsigned short f2bf(float f) {
    unsigned u = __float_as_uint(f);
    unsigned r = (u + 0x7FFF + ((u >> 16) & 1)) >> 16;
    return (unsigned short)r;
}
__device__ inline float bf2f(unsigned short h) {
    return __uint_as_float(((unsigned)h) << 16);
}

// weight split (runs twice per launch, small)
__global__ __launch_bounds__(256) void k_tobf16(const float* __restrict__ x,
                                                unsigned short* __restrict__ hi,
                                                unsigned short* __restrict__ lo, int n) {
    int i = blockIdx.x * 256 + threadIdx.x;
    int base = i * 4;
    if (base >= n) return;
    float4 v = *(const float4*)(x + base);
    float f[4] = {v.x, v.y, v.z, v.w};
    ushort4 h, l;
    unsigned short hh[4], ll[4];
    #pragma unroll
    for (int q = 0; q < 4; q++) {
        unsigned short a = f2bf(f[q]);
        hh[q] = a;
        ll[q] = f2bf(f[q] - bf2f(a));
    }
    h.x = hh[0]; h.y = hh[1]; h.z = hh[2]; h.w = hh[3];
    l.x = ll[0]; l.y = ll[1]; l.z = ll[2]; l.w = ll[3];
    *(ushort4*)(hi + base) = h;
    *(ushort4*)(lo + base) = l;
}

// ---------------- MFMA linear, LDS-resident W ----------------
// Split-precision: x*W ~= xh*Wh + xh*Wl + xl*Wh (bf16 MFMA, fp32 accumulate).
// blockIdx.y: 0 -> xlh (fp16!) = x@Wl.T+bl ; 1 -> xr (fp32) = x@Wr.T+br.
// xl is only consumed by the k_attn gather -> fp16 halves that traffic.
// Block = 512 threads (8 waves) = 128 nodes; W hi+lo (64 KB) in LDS with
// XOR-chunk swizzle (2-way bank aliasing = free, m136).

__global__ __launch_bounds__(512) void k_linear_mfma(
        const unsigned short* __restrict__ xhi, const unsigned short* __restrict__ xlo,
        const unsigned short* __restrict__ whiL, const unsigned short* __restrict__ wloL,
        const unsigned short* __restrict__ whiR, const unsigned short* __restrict__ wloR,
        const float* __restrict__ bl, const float* __restrict__ br,
        _Float16* __restrict__ xlh, float* __restrict__ xr, int N) {
    __shared__ unsigned short ldsh[16384];   // 32 KB: W hi, swizzled
    __shared__ unsigned short ldsl[16384];   // 32 KB: W lo, swizzled
    const int t   = threadIdx.x;
    const int mat = blockIdx.y;
    const unsigned short* Wh = mat ? whiR : whiL;
    const unsigned short* Wo = mat ? wloR : wloL;

    for (int g = t; g < 2048; g += 512) {
        int r = g >> 4, cc = g & 15;
        int dsto = r * 128 + ((cc ^ (r & 7)) << 3);      // ushort units
        *(float4*)&ldsh[dsto] = *(const float4*)(Wh + g * 8);
        *(float4*)&ldsl[dsto] = *(const float4*)(Wo + g * 8);
    }
    __syncthreads();

    const int wave = t >> 6;
    const int lane = t & 63;
    const int l16  = lane & 15;
    const int quad = lane >> 4;
    const int n0   = blockIdx.x * 128 + wave * 16;

    int arow = n0 + l16;
    if (arow >= N) arow = N - 1;       // clamp loads; stores guarded below

    f32x4 acc[8];
    #pragma unroll
    for (int s = 0; s < 8; s++) acc[s] = (f32x4){0.f, 0.f, 0.f, 0.f};

    #pragma unroll
    for (int k0 = 0; k0 < HID; k0 += 32) {
        const int aoff = arow * HID + k0 + quad * 8;
        bf16x8 ahi = *(const bf16x8*)(xhi + aoff);
        bf16x8 alo = *(const bf16x8*)(xlo + aoff);
        const int cc = (k0 >> 3) + quad;
        #pragma unroll
        for (int s = 0; s < 8; s++) {
            const int row = s * 16 + l16;
            const int off = row * 128 + ((cc ^ (l16 & 7)) << 3);
            bf16x8 bhi = *(const bf16x8*)&ldsh[off];
            bf16x8 blo = *(const bf16x8*)&ldsl[off];
            acc[s] = __builtin_amdgcn_mfma_f32_16x16x32_bf16(ahi, bhi, acc[s], 0, 0, 0);
            acc[s] = __builtin_amdgcn_mfma_f32_16x16x32_bf16(ahi, blo, acc[s], 0, 0, 0);
            acc[s] = __builtin_amdgcn_mfma_f32_16x16x32_bf16(alo, bhi, acc[s], 0, 0, 0);
        }
    }

    const float* bias = mat ? br : bl;
    #pragma unroll
    for (int s = 0; s < 8; s++) {
        int col = s * 16 + l16;
        float bv = bias[col];
        #pragma unroll
        for (int r = 0; r < 4; r++) {
            int node = n0 + quad * 4 + r;
            if (node < N) {
                float v = acc[s][r] + bv;
                if (mat) xr[(size_t)node * HID + col] = v;
                else     xlh[(size_t)node * HID + col] = (_Float16)v;
            }
        }
    }
}

// ---------------- Fused attention: wave per node, 2 edge streams ----------------
// fp16 xl gather (8 B/lane), no max-subtraction (|logit| <~ 3 << 88, exp-safe),
// 2-deep software prefetch. Epilogue emits bf16 hi/lo split for next linear.

__global__ __launch_bounds__(256) void k_attn(const _Float16* __restrict__ xlh, const float* __restrict__ xr,
                                              const int* __restrict__ rowptr, const int* __restrict__ csr_src,
                                              const float* __restrict__ att, const float* __restrict__ bias,
                                              const float* __restrict__ x_res, float* __restrict__ out,
                                              unsigned short* __restrict__ xhi, unsigned short* __restrict__ xlo,
                                              int add_res, int want_split, int N) {
    const int wave = threadIdx.x >> 6;
    const int lane = threadIdx.x & 63;
    const int sub  = lane >> 5;          // edge stream 0/1
    const int l32  = lane & 31;          // channels [4*l32, 4*l32+4); head = l32>>3
    const int n = blockIdx.x * 4 + wave;
    if (n >= N) return;

    const float4 a4  = *(const float4*)(att + 4 * l32);
    const float4 xr4 = *(const float4*)(xr + (size_t)n * HID + 4 * l32);
    const int s0 = rowptr[n], s1 = rowptr[n + 1];

    float den = 0.f;
    float4 acc = make_float4(0.f, 0.f, 0.f, 0.f);

    int j = s0 + sub;
    f16x4 p0 = (f16x4){0, 0, 0, 0}, p1 = (f16x4){0, 0, 0, 0};
    if (j < s1)     p0 = *(const f16x4*)(xlh + (size_t)csr_src[j] * HID + 4 * l32);
    if (j + 2 < s1) p1 = *(const f16x4*)(xlh + (size_t)csr_src[j + 2] * HID + 4 * l32);
    while (j < s1) {
        f16x4 curh = p0;
        p0 = p1;
        if (j + 4 < s1) p1 = *(const f16x4*)(xlh + (size_t)csr_src[j + 4] * HID + 4 * l32);
        float c0 = (float)curh[0], c1 = (float)curh[1], c2 = (float)curh[2], c3 = (float)curh[3];
        float e0 = c0 + xr4.x; e0 = e0 > 0.f ? e0 : NEG_SLOPE * e0;
        float e1 = c1 + xr4.y; e1 = e1 > 0.f ? e1 : NEG_SLOPE * e1;
        float e2 = c2 + xr4.z; e2 = e2 > 0.f ? e2 : NEG_SLOPE * e2;
        float e3 = c3 + xr4.w; e3 = e3 > 0.f ? e3 : NEG_SLOPE * e3;
        float p = e0 * a4.x + e1 * a4.y + e2 * a4.z + e3 * a4.w;
        p += __shfl_xor(p, 1);           // reduce 8-lane head group
        p += __shfl_xor(p, 2);
        p += __shfl_xor(p, 4);
        float w = __expf(p);
        den += w;
        acc.x += w * c0;
        acc.y += w * c1;
        acc.z += w * c2;
        acc.w += w * c3;
        j += 2;
    }

    // merge the two streams across the half-wave boundary (plain sums now)
    den   += __shfl_xor(den, 32);
    acc.x += __shfl_xor(acc.x, 32);
    acc.y += __shfl_xor(acc.y, 32);
    acc.z += __shfl_xor(acc.z, 32);
    acc.w += __shfl_xor(acc.w, 32);

    if (sub == 0) {
        float4 b4 = *(const float4*)(bias + 4 * l32);
        float inv = (den > 0.f) ? 1.f / den : 0.f;
        float4 v;
        v.x = fmaxf(acc.x * inv + b4.x, 0.f);
        v.y = fmaxf(acc.y * inv + b4.y, 0.f);
        v.z = fmaxf(acc.z * inv + b4.z, 0.f);
        v.w = fmaxf(acc.w * inv + b4.w, 0.f);
        if (add_res) {
            float4 r4 = *(const float4*)(x_res + (size_t)n * HID + 4 * l32);
            v.x += r4.x; v.y += r4.y; v.z += r4.z; v.w += r4.w;
        }
        *(float4*)(out + (size_t)n * HID + 4 * l32) = v;
        if (want_split) {
            float f[4] = {v.x, v.y, v.z, v.w};
            unsigned short hh[4], ll[4];
            #pragma unroll
            for (int q = 0; q < 4; q++) {
                unsigned short a = f2bf(f[q]);
                hh[q] = a;
                ll[q] = f2bf(f[q] - bf2f(a));
            }
            ushort4 h4, l4;
            h4.x = hh[0]; h4.y = hh[1]; h4.z = hh[2]; h4.w = hh[3];
            l4.x = ll[0]; l4.y = ll[1]; l4.z = ll[2]; l4.w = ll[3];
            *(ushort4*)(xhi + (size_t)n * HID + 4 * l32) = h4;
            *(ushort4*)(xlo + (size_t)n * HID + 4 * l32) = l4;
        }
    }
}

// ---------------- Embedding: x = relu(nf @ W_emb.T + b_emb)  (+ bf16 split) ----------------

__global__ __launch_bounds__(128) void k_embed(const float* __restrict__ nf, const float* __restrict__ W,
                                               const float* __restrict__ b, float* __restrict__ x,
                                               unsigned short* __restrict__ xhi, unsigned short* __restrict__ xlo,
                                               int N) {
    __shared__ float f[11];
    int n = blockIdx.x;
    int h = threadIdx.x;
    if (h < 11) f[h] = nf[(size_t)n * 11 + h];
    __syncthreads();
    float acc = b[h];
    #pragma unroll
    for (int k = 0; k < 11; k++) acc += f[k] * W[h * 11 + k];
    float v = fmaxf(acc, 0.f);
    x[(size_t)n * HID + h] = v;
    unsigned short hh = f2bf(v);
    xhi[(size_t)n * HID + h] = hh;
    xlo[(size_t)n * HID + h] = f2bf(v - bf2f(hh));
}

// ---------------- Graph readout: mean + max over nodes ----------------

__global__ __launch_bounds__(128) void k_reduce1(const float* __restrict__ x, int N,
                                                 float* __restrict__ psum, float* __restrict__ pmax) {
    int b = blockIdx.x;
    int h = threadIdx.x;
    int per = (N + gridDim.x - 1) / gridDim.x;
    int n0 = b * per, n1 = min(N, n0 + per);
    float s = 0.f, m = -INFINITY;
    for (int n = n0; n < n1; n++) {
        float v = x[(size_t)n * HID + h];
        s += v;
        m = fmaxf(m, v);
    }
    psum[b * HID + h] = s;
    pmax[b * HID + h] = m;
}

__global__ __launch_bounds__(128) void k_reduce2(const float* __restrict__ psum, const float* __restrict__ pmax,
                                                 int nb, float* __restrict__ out, float invN) {
    int h = threadIdx.x;
    float s = 0.f, m = -INFINITY;
    for (int b = 0; b < nb; b++) {
        s += psum[b * HID + h];
        m = fmaxf(m, pmax[b * HID + h]);
    }
    out[h] = s * invN;
    out[HID + h] = m;
}

// ---------------- Launch ----------------

extern "C" void kernel_launch(void* const* d_in, const int* in_sizes, int n_in,
                              void* d_out, int out_size, void* d_ws, size_t ws_size,
                              hipStream_t stream) {
    const float* nf    = (const float*)d_in[0];
    const int*   ei    = (const int*)d_in[1];
    const float* W_emb = (const float*)d_in[3];
    const float* b_emb = (const float*)d_in[4];
    const float* Wl    = (const float*)d_in[5];
    const float* bl    = (const float*)d_in[6];
    const float* Wr    = (const float*)d_in[7];
    const float* br    = (const float*)d_in[8];
    const float* att   = (const float*)d_in[9];
    const float* bias  = (const float*)d_in[10];

    const int N = in_sizes[0] / 11;
    const int E = in_sizes[1] / 2;
    const int* src = ei;
    const int* dst = ei + E;

    float* out  = (float*)d_out;
    float* xout = out + 2 * HID;

    // workspace carve-up
    char* w = (char*)d_ws;
    float* x        = (float*)w; w += (size_t)N * HID * 4;
    _Float16* xlh   = (_Float16*)w; w += (size_t)N * HID * 2;
    float* xr       = (float*)w; w += (size_t)N * HID * 4;
    unsigned short* xhi = (unsigned short*)w; w += (size_t)N * HID * 2;
    unsigned short* xlo = (unsigned short*)w; w += (size_t)N * HID * 2;
    unsigned short* whiL = (unsigned short*)w; w += (size_t)4 * HID * HID * 2;
    unsigned short* wloL = (unsigned short*)w; w += (size_t)4 * HID * HID * 2;
    unsigned short* whiR = (unsigned short*)w; w += (size_t)4 * HID * HID * 2;
    unsigned short* wloR = (unsigned short*)w; w += (size_t)4 * HID * HID * 2;
    int*   counts   = (int*)w;   w += (size_t)N * 4;
    int*   scanout  = (int*)w;   w += (size_t)N * 4;
    int*   rowptr   = (int*)w;   w += (size_t)(N + 1) * 4;
    int*   nextp    = (int*)w;   w += (size_t)N * 4;
    int*   partials = (int*)w;   w += (size_t)256 * 4;
    int*   csr_src  = (int*)w;   w += (size_t)E * 4;
    float* psum     = (float*)w; w += (size_t)256 * HID * 4;
    float* pmax     = (float*)w; w += (size_t)256 * HID * 4;

    const int nb = (N + 255) / 256;
    const int nW = 4 * HID * HID;

    // weight bf16 split (once per launch)
    k_tobf16<<<(nW / 4 + 255) / 256, 256, 0, stream>>>(Wl, whiL, wloL, nW);
    k_tobf16<<<(nW / 4 + 255) / 256, 256, 0, stream>>>(Wr, whiR, wloR, nW);

    // CSR build
    k_zero_int<<<nb, 256, 0, stream>>>(counts, N);
    k_hist<<<(E + 255) / 256, 256, 0, stream>>>(dst, E, counts);
    k_scan_block<<<nb, 256, 0, stream>>>(counts, N, scanout, partials);
    k_scan_part<<<1, 256, 0, stream>>>(partials, nb);
    k_scan_add<<<nb, 256, 0, stream>>>(scanout, partials, N, E, rowptr, nextp);
    k_scatter<<<(E + 255) / 256, 256, 0, stream>>>(src, dst, E, nextp, csr_src);

    // embedding (+ bf16 split of x)
    k_embed<<<N, 128, 0, stream>>>(nf, W_emb, b_emb, x, xhi, xlo, N);

    dim3 lgrid((N + 127) / 128, 2);
    for (int i = 0; i < 4; i++) {
        k_linear_mfma<<<lgrid, 512, 0, stream>>>(xhi, xlo,
                                                 whiL + (size_t)i * HID * HID, wloL + (size_t)i * HID * HID,
                                                 whiR + (size_t)i * HID * HID, wloR + (size_t)i * HID * HID,
                                                 bl + i * HID, br + i * HID, xlh, xr, N);
        float* dest = (i == 3) ? xout : x;
        k_attn<<<(N + 3) / 4, 256, 0, stream>>>(xlh, xr, rowptr, csr_src,
                                                att + i * HEADS * 32, bias + i * HID,
                                                x, dest, xhi, xlo,
                                                i > 0 ? 1 : 0, i < 3 ? 1 : 0, N);
    }

    k_reduce1<<<256, 128, 0, stream>>>(xout, N, psum, pmax);
    k_reduce2<<<1, 128, 0, stream>>>(psum, pmax, 256, out, 1.0f / N);
}